// Round 19
// baseline (668.427 us; speedup 1.0000x reference)
//
#include <hip/hip_runtime.h>
#include <stdint.h>

// LSTM B=256,T=2048,D=U=64 fp32. 256 WGs (1 batch) x 256 thr (4 waves).
// R19 = R15 (576us, best) + intra-step dependency cuts:
//  - 8 INDEPENDENT zero-C MFMAs (was 4 chains of 2): the A0-group issues
//    while A1's ds_read is in flight (compiler emits lgkmcnt(1) for it),
//    and the 2nd MFMA's latency leaves the critical chain. z = h[0]+hb[0]+xz.
//  - publish-first epilogue: sH h-write issued before global c/h stores so
//    the barrier's lgkm drain isn't queued behind them.
// Everything else identical to R15: replicated-A h-MFMA, xz per 16-step
// chunk via MFMA rows=timesteps into wave-private sXZ, xz[s+1] prefetch
// pre-barrier, one lgkm-only barrier per step, vmcnt never drained.
// k-map f(g,e)=g*8+e on BOTH A and B; C/D layout m89-verified.

#define T_STEPS 2048
#define DIM     64
#define GATES   256
#define CHUNK   16
#define NCHUNK  (T_STEPS / CHUNK)

typedef _Float16 f16;
typedef _Float16 f16x8 __attribute__((ext_vector_type(8)));
typedef float    f32x4 __attribute__((ext_vector_type(4)));

__device__ __forceinline__ void sync_lds() {
    __builtin_amdgcn_sched_barrier(0);
    asm volatile("s_waitcnt lgkmcnt(0)" ::: "memory");
    __builtin_amdgcn_sched_barrier(0);
    __builtin_amdgcn_s_barrier();
    __builtin_amdgcn_sched_barrier(0);
}

__device__ __forceinline__ float sigm(float z) {
    return __builtin_amdgcn_rcpf(1.f + __expf(-z));
}

#define MFMA16(A, B, C) __builtin_amdgcn_mfma_f32_16x16x32_f16(A, B, C, 0, 0, 0)

__device__ __forceinline__ void pack8(f16x8& d, const float4& a, const float4& b) {
    d[0]=(f16)a.x; d[1]=(f16)a.y; d[2]=(f16)a.z; d[3]=(f16)a.w;
    d[4]=(f16)b.x; d[5]=(f16)b.y; d[6]=(f16)b.z; d[7]=(f16)b.w;
}

__global__ __launch_bounds__(256, 1)
void lstm_r19_kernel(const float* __restrict__ x,
                     const float* __restrict__ Wx,
                     const float* __restrict__ Wh,
                     const float* __restrict__ bias,
                     float* __restrict__ out)
{
    __shared__ __align__(16) f16   sH[2][64];             // h dbuf (f16)
    __shared__ __align__(16) float sXZ[4][CHUNK][16][4];  // wave-private xz

    const int tid  = threadIdx.x;
    const int lane = tid & 63;
    const int w    = tid >> 6;       // wave 0..3 -> units w*16..+16
    const int j    = lane & 15;      // col-in-tile (B,D) / row (A, xz MFMA)
    const int g    = lane >> 4;      // k-group: k = ks*32 + g*8 + e
    const int u    = w * 16 + j;     // unit

    const int batch = blockIdx.x;
    const float* xb = x + (size_t)batch * T_STEPS * DIM;
    float* ob = out + (size_t)batch * T_STEPS * (2 * DIM);

    // ---- persistent B fragments: col = q*64 + u, k = ks*32 + g*8 + e ----
    f16x8 Bh[4][2], Bx[4][2];
    f32x4 bias4[4];
#pragma unroll
    for (int q = 0; q < 4; ++q) {
        const int col = q * 64 + u;
        const float bb = bias[col];
        bias4[q][0] = bb; bias4[q][1] = bb; bias4[q][2] = bb; bias4[q][3] = bb;
#pragma unroll
        for (int ks = 0; ks < 2; ++ks)
#pragma unroll
            for (int e = 0; e < 8; ++e) {
                const int k = ks * 32 + g * 8 + e;
                Bh[q][ks][e] = (f16)Wh[k * GATES + col];
                Bx[q][ks][e] = (f16)Wx[k * GATES + col];
            }
    }
    const f32x4 zero4 = {0.f, 0.f, 0.f, 0.f};

    if (tid < 128) sH[tid >> 6][tid & 63] = (f16)0.f;

    // ---- prefetch x chunk 0: A row = ts = j, feats g*8.. ----
    float4 x0, x1, x2, x3;
    {
        const float* xr = xb + (size_t)j * DIM + g * 8;
        x0 = *(const float4*)(xr);      x1 = *(const float4*)(xr + 4);
        x2 = *(const float4*)(xr + 32); x3 = *(const float4*)(xr + 36);
    }

    float c = 0.f;   // replicated: every lane-group's lane j holds c[u]
    __syncthreads();

#pragma unroll 1
    for (int n = 0; n < NCHUNK; ++n) {
        // ---- xz chunk: z[q] = bias + X_chunk @ Wx (rows = 16 ts) ----
        f16x8 ax0, ax1;
        pack8(ax0, x0, x1); pack8(ax1, x2, x3);
        f32x4 z0 = MFMA16(ax0, Bx[0][0], bias4[0]); z0 = MFMA16(ax1, Bx[0][1], z0);
        f32x4 z1 = MFMA16(ax0, Bx[1][0], bias4[1]); z1 = MFMA16(ax1, Bx[1][1], z1);
        f32x4 z2 = MFMA16(ax0, Bx[2][0], bias4[2]); z2 = MFMA16(ax1, Bx[2][1], z2);
        f32x4 z3 = MFMA16(ax0, Bx[3][0], bias4[3]); z3 = MFMA16(ax1, Bx[3][1], z3);
        // scatter to wave-private sXZ: row = 4g+r (D-layout), unit j
#pragma unroll
        for (int r = 0; r < 4; ++r) {
            float4 v = {z0[r], z1[r], z2[r], z3[r]};
            *(float4*)&sXZ[w][4 * g + r][j][0] = v;
        }
        // s=0 xz read: DS in-wave program order -> consistent, no drain
        float4 xzv = *(const float4*)&sXZ[w][0][j][0];

        // prefetch next chunk's x (returns during the 16 steps below)
        if (n + 1 < NCHUNK) {
            const float* xr = xb + ((size_t)(n + 1) * CHUNK + j) * DIM + g * 8;
            x0 = *(const float4*)(xr);      x1 = *(const float4*)(xr + 4);
            x2 = *(const float4*)(xr + 32); x3 = *(const float4*)(xr + 36);
        }

        float* obn = ob + (size_t)n * CHUNK * 128;

#pragma unroll
        for (int s = 0; s < CHUNK; ++s) {
            const int pb = s & 1;
            // A-reads FIRST post-barrier (the only LDS on the critical path)
            f16x8 A0 = *(const f16x8*)&sH[pb][g * 8];
            f16x8 A1 = *(const f16x8*)&sH[pb][32 + g * 8];

            // 8 INDEPENDENT zero-C MFMAs: A0-group issues under A1's
            // ds_read latency (lgkmcnt(1)); no serial 2-deep acc chain.
            f32x4 h0a = MFMA16(A0, Bh[0][0], zero4);
            f32x4 h1a = MFMA16(A0, Bh[1][0], zero4);
            f32x4 h2a = MFMA16(A0, Bh[2][0], zero4);
            f32x4 h3a = MFMA16(A0, Bh[3][0], zero4);
            f32x4 h0b = MFMA16(A1, Bh[0][1], zero4);
            f32x4 h1b = MFMA16(A1, Bh[1][1], zero4);
            f32x4 h2b = MFMA16(A1, Bh[2][1], zero4);
            f32x4 h3b = MFMA16(A1, Bh[3][1], zero4);

            float zi = (h0a[0] + h0b[0]) + xzv.x;
            float zf = (h1a[0] + h1b[0]) + xzv.y;
            float zg = (h2a[0] + h2b[0]) + xzv.z;
            float zo = (h3a[0] + h3b[0]) + xzv.w;
            float gi = sigm(zi), gf = sigm(zf), go = sigm(zo);
            float gg = fmaf(2.f, sigm(zg + zg), -1.f);
            c = fmaf(gf, c, gi * gg);
            float e2 = __expf(-2.f * fabsf(c));
            float th = copysignf(
                fmaf(-2.f, e2 * __builtin_amdgcn_rcpf(1.f + e2), 1.f), c);
            float hh = go * th;

            // next step's xz prefetch (wave-private, stable; s=15 discarded)
            float4 xzn = *(const float4*)&sXZ[w][(s + 1) & 15][j][0];

            // publish-first: the sH write is what the barrier orders
            if (g == 2)      sH[pb ^ 1][u] = (f16)hh;     // next-step h
            else if (g == 0) obn[s * 128 + u]      = c;   // cell out
            else if (g == 1) obn[s * 128 + 64 + u] = hh;  // hidden out
            sync_lds();
            xzv = xzn;
        }
    }
}

extern "C" void kernel_launch(void* const* d_in, const int* in_sizes, int n_in,
                              void* d_out, int out_size, void* d_ws, size_t ws_size,
                              hipStream_t stream) {
    const float* x  = (const float*)d_in[0];
    const float* Wx = (const float*)d_in[1];
    const float* Wh = (const float*)d_in[2];
    const float* b  = (const float*)d_in[3];
    float* out = (float*)d_out;

    hipLaunchKernelGGL(lstm_r19_kernel, dim3(256), dim3(256), 0, stream,
                       x, Wx, Wh, b, out);
}

// Round 20
// 542.283 us; speedup vs baseline: 1.2326x; 1.2326x over previous
//
#include <hip/hip_runtime.h>
#include <stdint.h>

// LSTM B=256,T=2048,D=U=64 fp32. 256 WGs (1 batch) x 256 thr (4 waves).
// R20 = R15 (576us, best) + store deferral ONLY:
//  - the two global stores (c, h) leave the pre-barrier critical tail and
//    are issued one step late, post-barrier, in the A-read latency shadow
//    (wave is lgkm-stalled there anyway). prev (c,hh) ride in 2 registers;
//    epilogue store after the loop.
// Everything else is R15 verbatim (R16-R19 all regressed): replicated-A
// h-MFMA with persistent zero-C 2-deep chains, xz per 16-step chunk via
// MFMA rows=timesteps into wave-private sXZ, xz[s+1] prefetch pre-barrier,
// one lgkm-only barrier per step, vmcnt never drained.
// k-map f(g,e)=g*8+e on BOTH A and B; C/D layout m89-verified.

#define T_STEPS 2048
#define DIM     64
#define GATES   256
#define CHUNK   16
#define NCHUNK  (T_STEPS / CHUNK)

typedef _Float16 f16;
typedef _Float16 f16x8 __attribute__((ext_vector_type(8)));
typedef float    f32x4 __attribute__((ext_vector_type(4)));

__device__ __forceinline__ void sync_lds() {
    __builtin_amdgcn_sched_barrier(0);
    asm volatile("s_waitcnt lgkmcnt(0)" ::: "memory");
    __builtin_amdgcn_sched_barrier(0);
    __builtin_amdgcn_s_barrier();
    __builtin_amdgcn_sched_barrier(0);
}

__device__ __forceinline__ float sigm(float z) {
    return __builtin_amdgcn_rcpf(1.f + __expf(-z));
}

#define MFMA16(A, B, C) __builtin_amdgcn_mfma_f32_16x16x32_f16(A, B, C, 0, 0, 0)

__device__ __forceinline__ void pack8(f16x8& d, const float4& a, const float4& b) {
    d[0]=(f16)a.x; d[1]=(f16)a.y; d[2]=(f16)a.z; d[3]=(f16)a.w;
    d[4]=(f16)b.x; d[5]=(f16)b.y; d[6]=(f16)b.z; d[7]=(f16)b.w;
}

__global__ __launch_bounds__(256, 1)
void lstm_r20_kernel(const float* __restrict__ x,
                     const float* __restrict__ Wx,
                     const float* __restrict__ Wh,
                     const float* __restrict__ bias,
                     float* __restrict__ out)
{
    __shared__ __align__(16) f16   sH[2][64];             // h dbuf (f16)
    __shared__ __align__(16) float sXZ[4][CHUNK][16][4];  // wave-private xz

    const int tid  = threadIdx.x;
    const int lane = tid & 63;
    const int w    = tid >> 6;       // wave 0..3 -> units w*16..+16
    const int j    = lane & 15;      // col-in-tile (B,D) / row (A, xz MFMA)
    const int g    = lane >> 4;      // k-group: k = ks*32 + g*8 + e
    const int u    = w * 16 + j;     // unit

    const int batch = blockIdx.x;
    const float* xb = x + (size_t)batch * T_STEPS * DIM;
    float* ob = out + (size_t)batch * T_STEPS * (2 * DIM);

    // ---- persistent B fragments: col = q*64 + u, k = ks*32 + g*8 + e ----
    f16x8 Bh[4][2], Bx[4][2];
    f32x4 bias4[4];
#pragma unroll
    for (int q = 0; q < 4; ++q) {
        const int col = q * 64 + u;
        const float bb = bias[col];
        bias4[q][0] = bb; bias4[q][1] = bb; bias4[q][2] = bb; bias4[q][3] = bb;
#pragma unroll
        for (int ks = 0; ks < 2; ++ks)
#pragma unroll
            for (int e = 0; e < 8; ++e) {
                const int k = ks * 32 + g * 8 + e;
                Bh[q][ks][e] = (f16)Wh[k * GATES + col];
                Bx[q][ks][e] = (f16)Wx[k * GATES + col];
            }
    }
    const f32x4 zero4 = {0.f, 0.f, 0.f, 0.f};

    if (tid < 128) sH[tid >> 6][tid & 63] = (f16)0.f;

    // ---- prefetch x chunk 0: A row = ts = j, feats g*8.. ----
    float4 x0, x1, x2, x3;
    {
        const float* xr = xb + (size_t)j * DIM + g * 8;
        x0 = *(const float4*)(xr);      x1 = *(const float4*)(xr + 4);
        x2 = *(const float4*)(xr + 32); x3 = *(const float4*)(xr + 36);
    }

    float c = 0.f;   // replicated: every lane-group's lane j holds c[u]
    float pc = 0.f, ph = 0.f;   // deferred-store copies of last step's (c,h)
    __syncthreads();

#pragma unroll 1
    for (int n = 0; n < NCHUNK; ++n) {
        // ---- xz chunk: z[q] = bias + X_chunk @ Wx (rows = 16 ts) ----
        f16x8 ax0, ax1;
        pack8(ax0, x0, x1); pack8(ax1, x2, x3);
        f32x4 z0 = MFMA16(ax0, Bx[0][0], bias4[0]); z0 = MFMA16(ax1, Bx[0][1], z0);
        f32x4 z1 = MFMA16(ax0, Bx[1][0], bias4[1]); z1 = MFMA16(ax1, Bx[1][1], z1);
        f32x4 z2 = MFMA16(ax0, Bx[2][0], bias4[2]); z2 = MFMA16(ax1, Bx[2][1], z2);
        f32x4 z3 = MFMA16(ax0, Bx[3][0], bias4[3]); z3 = MFMA16(ax1, Bx[3][1], z3);
        // scatter to wave-private sXZ: row = 4g+r (D-layout), unit j
#pragma unroll
        for (int r = 0; r < 4; ++r) {
            float4 v = {z0[r], z1[r], z2[r], z3[r]};
            *(float4*)&sXZ[w][4 * g + r][j][0] = v;
        }
        // s=0 xz read: DS in-wave program order -> consistent, no drain
        float4 xzv = *(const float4*)&sXZ[w][0][j][0];

        // prefetch next chunk's x (returns during the 16 steps below)
        if (n + 1 < NCHUNK) {
            const float* xr = xb + ((size_t)(n + 1) * CHUNK + j) * DIM + g * 8;
            x0 = *(const float4*)(xr);      x1 = *(const float4*)(xr + 4);
            x2 = *(const float4*)(xr + 32); x3 = *(const float4*)(xr + 36);
        }

        float* obn = ob + (size_t)n * CHUNK * 128;

#pragma unroll
        for (int s = 0; s < CHUNK; ++s) {
            const int pb = s & 1;
            // A-reads FIRST post-barrier (the only LDS on the critical path)
            f16x8 A0 = *(const f16x8*)&sH[pb][g * 8];
            f16x8 A1 = *(const f16x8*)&sH[pb][32 + g * 8];

            // deferred store of step t-1 (fills the A-read latency shadow)
            if (s > 0 || n > 0) {
                float* prevP = obn + (s - 1) * 128;       // s==0 -> prev chunk
                if (g == 0)      prevP[u]      = pc;       // cell out
                else if (g == 1) prevP[64 + u] = ph;       // hidden out
            }

            f32x4 h0 = MFMA16(A0, Bh[0][0], zero4); h0 = MFMA16(A1, Bh[0][1], h0);
            f32x4 h1 = MFMA16(A0, Bh[1][0], zero4); h1 = MFMA16(A1, Bh[1][1], h1);
            f32x4 h2 = MFMA16(A0, Bh[2][0], zero4); h2 = MFMA16(A1, Bh[2][1], h2);
            f32x4 h3 = MFMA16(A0, Bh[3][0], zero4); h3 = MFMA16(A1, Bh[3][1], h3);

            float zi = h0[0] + xzv.x, zf = h1[0] + xzv.y;
            float zg = h2[0] + xzv.z, zo = h3[0] + xzv.w;
            float gi = sigm(zi), gf = sigm(zf), go = sigm(zo);
            float gg = fmaf(2.f, sigm(zg + zg), -1.f);
            c = fmaf(gf, c, gi * gg);
            float e2 = __expf(-2.f * fabsf(c));
            float th = copysignf(
                fmaf(-2.f, e2 * __builtin_amdgcn_rcpf(1.f + e2), 1.f), c);
            float hh = go * th;

            // next step's xz prefetch (wave-private, stable; s=15 discarded)
            float4 xzn = *(const float4*)&sXZ[w][(s + 1) & 15][j][0];

            // pre-barrier tail: ONLY the h publication (what the barrier orders)
            if (g == 2) sH[pb ^ 1][u] = (f16)hh;
            pc = c; ph = hh;
            sync_lds();
            xzv = xzn;
        }
    }
    // epilogue: store final step t = T-1
    {
        float* prevP = ob + (size_t)(T_STEPS - 1) * 128;
        if (g == 0)      prevP[u]      = pc;
        else if (g == 1) prevP[64 + u] = ph;
    }
}

extern "C" void kernel_launch(void* const* d_in, const int* in_sizes, int n_in,
                              void* d_out, int out_size, void* d_ws, size_t ws_size,
                              hipStream_t stream) {
    const float* x  = (const float*)d_in[0];
    const float* Wx = (const float*)d_in[1];
    const float* Wh = (const float*)d_in[2];
    const float* b  = (const float*)d_in[3];
    float* out = (float*)d_out;

    hipLaunchKernelGGL(lstm_r20_kernel, dim3(256), dim3(256), 0, stream,
                       x, Wx, Wh, b, out);
}

// Round 21
// 521.260 us; speedup vs baseline: 1.2823x; 1.0403x over previous
//
#include <hip/hip_runtime.h>
#include <stdint.h>

// LSTM B=256,T=2048,D=U=64 fp32. 256 WGs (1 batch) x 256 thr (4 waves).
// R21 = R20 (542us, best) + two cuts:
//  1) counted lgkm barrier: pre-barrier tail is [sH write] -> [xzn read] ->
//     s_waitcnt lgkmcnt(1) -> s_barrier. In-order DS completion means the
//     write is drained while the xzn prefetch read stays IN FLIGHT across
//     the barrier (returns under next step's A-read waits). R20's
//     lgkmcnt(0) wasted ~60-100cyc/step waiting for that read.
//     Non-writer lanes (g!=2) have only the read outstanding -> zero wait.
//  2) exp2 pre-scaling: Wx, Wh, bias scaled by log2(e) at fragment load ->
//     z is in log2 units; activations use v_exp_f32 directly (no per-gate
//     mul). tanh(c) folds -2*log2e into one constant mul.
// Everything else = R20: replicated-A h-MFMA (persistent zero-C, 2-deep),
// xz per 16-step chunk via MFMA rows=timesteps into wave-private sXZ,
// deferred global stores (issued in next step's A-read shadow), one
// barrier per step, vmcnt never drained.
// k-map f(g,e)=g*8+e on BOTH A and B; C/D layout m89-verified.

#define T_STEPS 2048
#define DIM     64
#define GATES   256
#define CHUNK   16
#define NCHUNK  (T_STEPS / CHUNK)

typedef _Float16 f16;
typedef _Float16 f16x8 __attribute__((ext_vector_type(8)));
typedef float    f32x4 __attribute__((ext_vector_type(4)));

#define LOG2E   1.44269504088896f
#define N2LOG2E 2.88539008177793f   // 2*log2(e)

__device__ __forceinline__ float sigm2(float zl) {   // zl = z*log2e
    return __builtin_amdgcn_rcpf(1.f + __builtin_amdgcn_exp2f(-zl));
}

#define MFMA16(A, B, C) __builtin_amdgcn_mfma_f32_16x16x32_f16(A, B, C, 0, 0, 0)

__device__ __forceinline__ void pack8(f16x8& d, const float4& a, const float4& b) {
    d[0]=(f16)a.x; d[1]=(f16)a.y; d[2]=(f16)a.z; d[3]=(f16)a.w;
    d[4]=(f16)b.x; d[5]=(f16)b.y; d[6]=(f16)b.z; d[7]=(f16)b.w;
}

__global__ __launch_bounds__(256, 1)
void lstm_r21_kernel(const float* __restrict__ x,
                     const float* __restrict__ Wx,
                     const float* __restrict__ Wh,
                     const float* __restrict__ bias,
                     float* __restrict__ out)
{
    __shared__ __align__(16) f16   sH[2][64];             // h dbuf (f16)
    __shared__ __align__(16) float sXZ[4][CHUNK][16][4];  // wave-private xz

    const int tid  = threadIdx.x;
    const int lane = tid & 63;
    const int w    = tid >> 6;       // wave 0..3 -> units w*16..+16
    const int j    = lane & 15;      // col-in-tile (B,D) / row (A, xz MFMA)
    const int g    = lane >> 4;      // k-group: k = ks*32 + g*8 + e
    const int u    = w * 16 + j;     // unit

    const int batch = blockIdx.x;
    const float* xb = x + (size_t)batch * T_STEPS * DIM;
    float* ob = out + (size_t)batch * T_STEPS * (2 * DIM);

    // ---- persistent B fragments (scaled by log2e): col = q*64 + u ----
    f16x8 Bh[4][2], Bx[4][2];
    f32x4 bias4[4];
#pragma unroll
    for (int q = 0; q < 4; ++q) {
        const int col = q * 64 + u;
        const float bb = bias[col] * LOG2E;
        bias4[q][0] = bb; bias4[q][1] = bb; bias4[q][2] = bb; bias4[q][3] = bb;
#pragma unroll
        for (int ks = 0; ks < 2; ++ks)
#pragma unroll
            for (int e = 0; e < 8; ++e) {
                const int k = ks * 32 + g * 8 + e;
                Bh[q][ks][e] = (f16)(Wh[k * GATES + col] * LOG2E);
                Bx[q][ks][e] = (f16)(Wx[k * GATES + col] * LOG2E);
            }
    }
    const f32x4 zero4 = {0.f, 0.f, 0.f, 0.f};

    if (tid < 128) sH[tid >> 6][tid & 63] = (f16)0.f;

    // ---- prefetch x chunk 0: A row = ts = j, feats g*8.. ----
    float4 x0, x1, x2, x3;
    {
        const float* xr = xb + (size_t)j * DIM + g * 8;
        x0 = *(const float4*)(xr);      x1 = *(const float4*)(xr + 4);
        x2 = *(const float4*)(xr + 32); x3 = *(const float4*)(xr + 36);
    }

    float c = 0.f;   // replicated: every lane-group's lane j holds c[u]
    float pc = 0.f, ph = 0.f;   // deferred-store copies of last step's (c,h)
    __syncthreads();

#pragma unroll 1
    for (int n = 0; n < NCHUNK; ++n) {
        // ---- xz chunk: z[q] = bias + X_chunk @ Wx (rows = 16 ts) ----
        f16x8 ax0, ax1;
        pack8(ax0, x0, x1); pack8(ax1, x2, x3);
        f32x4 z0 = MFMA16(ax0, Bx[0][0], bias4[0]); z0 = MFMA16(ax1, Bx[0][1], z0);
        f32x4 z1 = MFMA16(ax0, Bx[1][0], bias4[1]); z1 = MFMA16(ax1, Bx[1][1], z1);
        f32x4 z2 = MFMA16(ax0, Bx[2][0], bias4[2]); z2 = MFMA16(ax1, Bx[2][1], z2);
        f32x4 z3 = MFMA16(ax0, Bx[3][0], bias4[3]); z3 = MFMA16(ax1, Bx[3][1], z3);
        // scatter to wave-private sXZ: row = 4g+r (D-layout), unit j
#pragma unroll
        for (int r = 0; r < 4; ++r) {
            float4 v = {z0[r], z1[r], z2[r], z3[r]};
            *(float4*)&sXZ[w][4 * g + r][j][0] = v;
        }
        // s=0 xz read: DS in-wave program order -> consistent, no drain
        float4 xzv = *(const float4*)&sXZ[w][0][j][0];

        // prefetch next chunk's x (returns during the 16 steps below)
        if (n + 1 < NCHUNK) {
            const float* xr = xb + ((size_t)(n + 1) * CHUNK + j) * DIM + g * 8;
            x0 = *(const float4*)(xr);      x1 = *(const float4*)(xr + 4);
            x2 = *(const float4*)(xr + 32); x3 = *(const float4*)(xr + 36);
        }

        float* obn = ob + (size_t)n * CHUNK * 128;

#pragma unroll
        for (int s = 0; s < CHUNK; ++s) {
            const int pb = s & 1;
            // A-reads FIRST post-barrier (the only LDS on the critical path)
            f16x8 A0 = *(const f16x8*)&sH[pb][g * 8];
            f16x8 A1 = *(const f16x8*)&sH[pb][32 + g * 8];

            // deferred store of step t-1 (fills the A-read latency shadow)
            if (s > 0 || n > 0) {
                float* prevP = obn + (s - 1) * 128;       // s==0 -> prev chunk
                if (g == 0)      prevP[u]      = pc;       // cell out
                else if (g == 1) prevP[64 + u] = ph;       // hidden out
            }

            f32x4 h0 = MFMA16(A0, Bh[0][0], zero4); h0 = MFMA16(A1, Bh[0][1], h0);
            f32x4 h1 = MFMA16(A0, Bh[1][0], zero4); h1 = MFMA16(A1, Bh[1][1], h1);
            f32x4 h2 = MFMA16(A0, Bh[2][0], zero4); h2 = MFMA16(A1, Bh[2][1], h2);
            f32x4 h3 = MFMA16(A0, Bh[3][0], zero4); h3 = MFMA16(A1, Bh[3][1], h3);

            float zi = h0[0] + xzv.x, zf = h1[0] + xzv.y;
            float zg = h2[0] + xzv.z, zo = h3[0] + xzv.w;
            float gi = sigm2(zi), gf = sigm2(zf), go = sigm2(zo);
            float gg = fmaf(2.f, sigm2(zg + zg), -1.f);
            c = fmaf(gf, c, gi * gg);
            float e2 = __builtin_amdgcn_exp2f(-N2LOG2E * fabsf(c));
            float th = copysignf(
                fmaf(-2.f, e2 * __builtin_amdgcn_rcpf(1.f + e2), 1.f), c);
            float hh = go * th;

            // ---- counted-lgkm barrier sequence ----
            // (1) publish h FIRST (the only DS op the barrier must drain)
            if (g == 2) sH[pb ^ 1][u] = (f16)hh;
            __builtin_amdgcn_sched_barrier(0);
            // (2) THEN issue next step's xz prefetch (stays in flight)
            float4 xzn = *(const float4*)&sXZ[w][(s + 1) & 15][j][0];
            __builtin_amdgcn_sched_barrier(0);
            // (3) wait write-drain only: in-order DS completion means
            //     lgkmcnt(1) => the write (issued first) has completed.
            asm volatile("s_waitcnt lgkmcnt(1)" ::: "memory");
            __builtin_amdgcn_sched_barrier(0);
            __builtin_amdgcn_s_barrier();
            __builtin_amdgcn_sched_barrier(0);

            pc = c; ph = hh;
            xzv = xzn;
        }
    }
    // epilogue: store final step t = T-1
    {
        float* prevP = ob + (size_t)(T_STEPS - 1) * 128;
        if (g == 0)      prevP[u]      = pc;
        else if (g == 1) prevP[64 + u] = ph;
    }
}

extern "C" void kernel_launch(void* const* d_in, const int* in_sizes, int n_in,
                              void* d_out, int out_size, void* d_ws, size_t ws_size,
                              hipStream_t stream) {
    const float* x  = (const float*)d_in[0];
    const float* Wx = (const float*)d_in[1];
    const float* Wh = (const float*)d_in[2];
    const float* b  = (const float*)d_in[3];
    float* out = (float*)d_out;

    hipLaunchKernelGGL(lstm_r21_kernel, dim3(256), dim3(256), 0, stream,
                       x, Wx, Wh, b, out);
}

// Round 22
// 497.029 us; speedup vs baseline: 1.3448x; 1.0488x over previous
//
#include <hip/hip_runtime.h>
#include <stdint.h>

// LSTM B=256,T=2048,D=U=64 fp32. 256 WGs (1 batch) x 256 thr (4 waves).
// R22 = R21 (521us, best) + serial-chain micro-trims:
//  1) branch-free tanh: th = 1 - 2*rcp(1 + exp2(k*c)); exp2 saturates to
//     0/inf so sign handling is implicit (fabsf/copysign/one mul removed
//     from the c->h serial chain).
//  2) candidate gate (q==2) weights/bias/xz pre-scaled by 2*log2e at load
//     -> per-step zg+zg add removed; gg = fmaf(2, sigm2(zg), -1).
// Everything else = R21: counted-lgkm barrier (write-first, then xz read,
// lgkmcnt(1)), exp2 pre-scaling (log2e folded into weights), replicated-A
// h-MFMA (persistent zero-C, 2-deep), xz per 16-step chunk via MFMA
// rows=timesteps into wave-private sXZ, deferred global stores in the
// A-read shadow, one barrier per step, vmcnt never drained.
// k-map f(g,e)=g*8+e on BOTH A and B; C/D layout m89-verified.

#define T_STEPS 2048
#define DIM     64
#define GATES   256
#define CHUNK   16
#define NCHUNK  (T_STEPS / CHUNK)

typedef _Float16 f16;
typedef _Float16 f16x8 __attribute__((ext_vector_type(8)));
typedef float    f32x4 __attribute__((ext_vector_type(4)));

#define LOG2E   1.44269504088896f
#define N2LOG2E 2.88539008177793f   // 2*log2(e)

__device__ __forceinline__ float sigm2(float zl) {   // zl = z*log2e
    return __builtin_amdgcn_rcpf(1.f + __builtin_amdgcn_exp2f(-zl));
}

#define MFMA16(A, B, C) __builtin_amdgcn_mfma_f32_16x16x32_f16(A, B, C, 0, 0, 0)

__device__ __forceinline__ void pack8(f16x8& d, const float4& a, const float4& b) {
    d[0]=(f16)a.x; d[1]=(f16)a.y; d[2]=(f16)a.z; d[3]=(f16)a.w;
    d[4]=(f16)b.x; d[5]=(f16)b.y; d[6]=(f16)b.z; d[7]=(f16)b.w;
}

__global__ __launch_bounds__(256, 1)
void lstm_r22_kernel(const float* __restrict__ x,
                     const float* __restrict__ Wx,
                     const float* __restrict__ Wh,
                     const float* __restrict__ bias,
                     float* __restrict__ out)
{
    __shared__ __align__(16) f16   sH[2][64];             // h dbuf (f16)
    __shared__ __align__(16) float sXZ[4][CHUNK][16][4];  // wave-private xz

    const int tid  = threadIdx.x;
    const int lane = tid & 63;
    const int w    = tid >> 6;       // wave 0..3 -> units w*16..+16
    const int j    = lane & 15;      // col-in-tile (B,D) / row (A, xz MFMA)
    const int g    = lane >> 4;      // k-group: k = ks*32 + g*8 + e
    const int u    = w * 16 + j;     // unit

    const int batch = blockIdx.x;
    const float* xb = x + (size_t)batch * T_STEPS * DIM;
    float* ob = out + (size_t)batch * T_STEPS * (2 * DIM);

    // ---- persistent B fragments, pre-scaled: gate q scale = log2e, except
    // candidate gate (q==2) scale = 2*log2e (removes per-step zg doubling).
    f16x8 Bh[4][2], Bx[4][2];
    f32x4 bias4[4];
#pragma unroll
    for (int q = 0; q < 4; ++q) {
        const float sc = (q == 2) ? N2LOG2E : LOG2E;
        const int col = q * 64 + u;
        const float bb = bias[col] * sc;
        bias4[q][0] = bb; bias4[q][1] = bb; bias4[q][2] = bb; bias4[q][3] = bb;
#pragma unroll
        for (int ks = 0; ks < 2; ++ks)
#pragma unroll
            for (int e = 0; e < 8; ++e) {
                const int k = ks * 32 + g * 8 + e;
                Bh[q][ks][e] = (f16)(Wh[k * GATES + col] * sc);
                Bx[q][ks][e] = (f16)(Wx[k * GATES + col] * sc);
            }
    }
    const f32x4 zero4 = {0.f, 0.f, 0.f, 0.f};

    if (tid < 128) sH[tid >> 6][tid & 63] = (f16)0.f;

    // ---- prefetch x chunk 0: A row = ts = j, feats g*8.. ----
    float4 x0, x1, x2, x3;
    {
        const float* xr = xb + (size_t)j * DIM + g * 8;
        x0 = *(const float4*)(xr);      x1 = *(const float4*)(xr + 4);
        x2 = *(const float4*)(xr + 32); x3 = *(const float4*)(xr + 36);
    }

    float c = 0.f;   // replicated: every lane-group's lane j holds c[u]
    float pc = 0.f, ph = 0.f;   // deferred-store copies of last step's (c,h)
    __syncthreads();

#pragma unroll 1
    for (int n = 0; n < NCHUNK; ++n) {
        // ---- xz chunk: z[q] = bias + X_chunk @ Wx (rows = 16 ts) ----
        f16x8 ax0, ax1;
        pack8(ax0, x0, x1); pack8(ax1, x2, x3);
        f32x4 z0 = MFMA16(ax0, Bx[0][0], bias4[0]); z0 = MFMA16(ax1, Bx[0][1], z0);
        f32x4 z1 = MFMA16(ax0, Bx[1][0], bias4[1]); z1 = MFMA16(ax1, Bx[1][1], z1);
        f32x4 z2 = MFMA16(ax0, Bx[2][0], bias4[2]); z2 = MFMA16(ax1, Bx[2][1], z2);
        f32x4 z3 = MFMA16(ax0, Bx[3][0], bias4[3]); z3 = MFMA16(ax1, Bx[3][1], z3);
        // scatter to wave-private sXZ: row = 4g+r (D-layout), unit j
#pragma unroll
        for (int r = 0; r < 4; ++r) {
            float4 v = {z0[r], z1[r], z2[r], z3[r]};
            *(float4*)&sXZ[w][4 * g + r][j][0] = v;
        }
        // s=0 xz read: DS in-wave program order -> consistent, no drain
        float4 xzv = *(const float4*)&sXZ[w][0][j][0];

        // prefetch next chunk's x (returns during the 16 steps below)
        if (n + 1 < NCHUNK) {
            const float* xr = xb + ((size_t)(n + 1) * CHUNK + j) * DIM + g * 8;
            x0 = *(const float4*)(xr);      x1 = *(const float4*)(xr + 4);
            x2 = *(const float4*)(xr + 32); x3 = *(const float4*)(xr + 36);
        }

        float* obn = ob + (size_t)n * CHUNK * 128;

#pragma unroll
        for (int s = 0; s < CHUNK; ++s) {
            const int pb = s & 1;
            // A-reads FIRST post-barrier (the only LDS on the critical path)
            f16x8 A0 = *(const f16x8*)&sH[pb][g * 8];
            f16x8 A1 = *(const f16x8*)&sH[pb][32 + g * 8];

            // deferred store of step t-1 (fills the A-read latency shadow)
            if (s > 0 || n > 0) {
                float* prevP = obn + (s - 1) * 128;       // s==0 -> prev chunk
                if (g == 0)      prevP[u]      = pc;       // cell out
                else if (g == 1) prevP[64 + u] = ph;       // hidden out
            }

            f32x4 h0 = MFMA16(A0, Bh[0][0], zero4); h0 = MFMA16(A1, Bh[0][1], h0);
            f32x4 h1 = MFMA16(A0, Bh[1][0], zero4); h1 = MFMA16(A1, Bh[1][1], h1);
            f32x4 h2 = MFMA16(A0, Bh[2][0], zero4); h2 = MFMA16(A1, Bh[2][1], h2);
            f32x4 h3 = MFMA16(A0, Bh[3][0], zero4); h3 = MFMA16(A1, Bh[3][1], h3);

            float zi = h0[0] + xzv.x, zf = h1[0] + xzv.y;
            float zg = h2[0] + xzv.z, zo = h3[0] + xzv.w;
            float gi = sigm2(zi), gf = sigm2(zf), go = sigm2(zo);
            float gg = fmaf(2.f, sigm2(zg), -1.f);     // zg pre-doubled
            c = fmaf(gf, c, gi * gg);
            // branch-free tanh: exp2 saturates (0/inf) -> sign implicit
            float ep = __builtin_amdgcn_exp2f(N2LOG2E * c);
            float th = fmaf(-2.f, __builtin_amdgcn_rcpf(1.f + ep), 1.f);
            float hh = go * th;

            // ---- counted-lgkm barrier sequence ----
            if (g == 2) sH[pb ^ 1][u] = (f16)hh;          // publish FIRST
            __builtin_amdgcn_sched_barrier(0);
            float4 xzn = *(const float4*)&sXZ[w][(s + 1) & 15][j][0];
            __builtin_amdgcn_sched_barrier(0);
            asm volatile("s_waitcnt lgkmcnt(1)" ::: "memory");
            __builtin_amdgcn_sched_barrier(0);
            __builtin_amdgcn_s_barrier();
            __builtin_amdgcn_sched_barrier(0);

            pc = c; ph = hh;
            xzv = xzn;
        }
    }
    // epilogue: store final step t = T-1
    {
        float* prevP = ob + (size_t)(T_STEPS - 1) * 128;
        if (g == 0)      prevP[u]      = pc;
        else if (g == 1) prevP[64 + u] = ph;
    }
}

extern "C" void kernel_launch(void* const* d_in, const int* in_sizes, int n_in,
                              void* d_out, int out_size, void* d_ws, size_t ws_size,
                              hipStream_t stream) {
    const float* x  = (const float*)d_in[0];
    const float* Wx = (const float*)d_in[1];
    const float* Wh = (const float*)d_in[2];
    const float* b  = (const float*)d_in[3];
    float* out = (float*)d_out;

    hipLaunchKernelGGL(lstm_r22_kernel, dim3(256), dim3(256), 0, stream,
                       x, Wx, Wh, b, out);
}